// Round 3
// baseline (1795.889 us; speedup 1.0000x reference)
//
#include <hip/hip_runtime.h>
#include <hip/hip_bf16.h>
#include <math.h>

#define DEV __device__ __forceinline__

DEV float sigmoidf_(float x) { return 1.0f / (1.0f + __expf(-x)); }

// Row-iteration macros: every per-row access is a literal constant index so
// SROA promotes all state to registers (runtime-indexed locals -> scratch,
// which was the round-1/2 disaster: 590 MB of scratch writes).
#define R10(OP) OP(0) OP(1) OP(2) OP(3) OP(4) OP(5) OP(6) OP(7) OP(8) OP(9)
#define R11(OP) R10(OP) OP(10)

// dot of sA[base..base+9] with hO scalars
#define DOT_O(base) (sA[(base)+0]*hO0 + sA[(base)+1]*hO1 + sA[(base)+2]*hO2 + sA[(base)+3]*hO3 \
                   + sA[(base)+4]*hO4 + sA[(base)+5]*hO5 + sA[(base)+6]*hO6 + sA[(base)+7]*hO7 \
                   + sA[(base)+8]*hO8 + sA[(base)+9]*hO9)
// dot of sA[base..base+10] with hD scalars
#define DOT_D(base) (sA[(base)+0]*hD0 + sA[(base)+1]*hD1 + sA[(base)+2]*hD2 + sA[(base)+3]*hD3 \
                   + sA[(base)+4]*hD4 + sA[(base)+5]*hD5 + sA[(base)+6]*hD6 + sA[(base)+7]*hD7 \
                   + sA[(base)+8]*hD8 + sA[(base)+9]*hD9 + sA[(base)+10]*hD10)

DEV float gstep(float x, float h, const float* k, const float* rk, const float* bb) {
  const float z  = sigmoidf_(fmaf(x, k[0], bb[0]) + fmaf(h, rk[0], bb[3]));
  const float r  = sigmoidf_(fmaf(x, k[1], bb[1]) + fmaf(h, rk[1], bb[4]));
  const float hh = tanhf(fmaf(x, k[2], bb[2]) + r * fmaf(h, rk[2], bb[5]));
  return z * h + (1.f - z) * hh;
}

// 3 tiny sequential bidirectional GRU chains + softmax + gather -> tp[3][60]
__global__ void __launch_bounds__(64, 1)
temporal_kernel(const float* __restrict__ T, const float* __restrict__ GK,
                const float* __restrict__ GRK, const float* __restrict__ GB,
                const float* __restrict__ WO, const int* __restrict__ IDX,
                float* __restrict__ tp) {
  const int i = threadIdx.x;
  __shared__ float fb[3][75];
  __shared__ float gg[3][75];
  if (i < 3) {
    float k0[3], k1[3], rk0[3], rk1[3];
#pragma unroll
    for (int q = 0; q < 3; ++q) {
      k0[q]  = GK[i * 6 + q];      k1[q]  = GK[i * 6 + 3 + q];
      rk0[q] = GRK[i * 6 + q];     rk1[q] = GRK[i * 6 + 3 + q];
    }
    const float* B0 = GB + i * 12;      // [p][q] for scan 0
    const float* B1 = GB + i * 12 + 6;  // [p][q] for scan 1
    float h = 0.f;
    for (int s = 0; s < 75; ++s) { h = gstep(T[i * 75 + s], h, k0, rk0, B0); fb[i][s] = h; }
    h = 0.f;
    for (int s = 0; s < 75; ++s) { h = gstep(fb[i][74 - s], h, k1, rk1, B1); gg[i][s] = h; }
    const float wo = WO[i];
    float mx = -1e30f;
    for (int s = 0; s < 75; ++s) mx = fmaxf(mx, gg[i][s] * wo);
    float sum = 0.f;
    for (int s = 0; s < 75; ++s) { const float e = __expf(gg[i][s] * wo - mx); fb[i][s] = e; sum += e; }
    const float inv = 1.f / sum;
    for (int j = 0; j < 60; ++j) tp[i * 60 + j] = fb[i][IDX[j]] * inv;
  }
}

// One wave (64 threads) per batch element. lane = feature column c.
// All per-row state lives in NAMED SCALARS (no local arrays -> no scratch).
__global__ void __launch_bounds__(64, 2) ggnn_main(
    const float* __restrict__ X, const float* __restrict__ A,
    const float* __restrict__ WgR, const float* __restrict__ bgR,
    const float* __restrict__ WgO, const float* __restrict__ bgO,
    const float* __restrict__ WgD, const float* __restrict__ bgD,
    const float* __restrict__ WzR, const float* __restrict__ WrR,
    const float* __restrict__ WmR, const float* __restrict__ bmR,
    const float* __restrict__ WzO, const float* __restrict__ WrO,
    const float* __restrict__ WmO, const float* __restrict__ bmO,
    const float* __restrict__ WzD, const float* __restrict__ WrD,
    const float* __restrict__ WmD, const float* __restrict__ bmD,
    const float* __restrict__ W1R, const float* __restrict__ b1R, const float* __restrict__ W2R,
    const float* __restrict__ W1O, const float* __restrict__ b1O, const float* __restrict__ W2O,
    const float* __restrict__ W1D, const float* __restrict__ b1D, const float* __restrict__ W2D,
    const float* __restrict__ tp, float* __restrict__ out) {
  const int b = blockIdx.x;
  const int c = threadIdx.x;  // 0..63

  __shared__ __align__(16) float smem[1920];  // X stage (880) / gate staging (<=10x192)
  __shared__ float sA[484];                   // A[b] 22x22

  const float* Xb = X + (size_t)b * 880;
  const float* Ab = A + (size_t)b * 484;
  for (int t = c; t < 880; t += 64) smem[t] = Xb[t];
  for (int t = c; t < 484; t += 64) sA[t] = Ab[t];
  __syncthreads();

  // ---------------- phase 0: h = tanh(Xg @ Wg + bg) ----------------
  float hR;
#define DECLHO(i) float hO##i;
  R10(DECLHO)
#undef DECLHO
#define DECLHD(i) float hD##i;
  R11(DECLHD)
#undef DECLHD
  {
    float aR = bgR[c], cO = bgO[c], cD = bgD[c];
#pragma unroll
    for (int k = 0; k < 40; ++k) {
      const float x = smem[k];  // X[b,0,k] broadcast
      aR = fmaf(x, WgR[k * 64 + c], aR);
      cO = fmaf(x, WgO[k * 64 + c], cO);
      cD = fmaf(x, WgD[k * 64 + c], cD);
    }
    hR = tanhf(aR);
#define DECLAO(i) float aO##i = cO;
    R10(DECLAO)
#undef DECLAO
#define DECLAD(i) float aD##i = cD;
    R11(DECLAD)
#undef DECLAD
    for (int k = 0; k < 30; ++k) {
      const float wo_ = WgO[(40 + k) * 64 + c];
      const float wd_ = WgD[(40 + k) * 64 + c];
#define AOSTEP(i) aO##i = fmaf(smem[(1 + i) * 40 + 10 + k], wo_, aO##i);
      R10(AOSTEP)
#undef AOSTEP
#define ADSTEP(i) aD##i = fmaf(smem[(11 + i) * 40 + 10 + k], wd_, aD##i);
      R11(ADSTEP)
#undef ADSTEP
    }
#define TANHO(i) hO##i = tanhf(aO##i);
    R10(TANHO)
#undef TANHO
#define TANHD(i) hD##i = tanhf(aD##i);
    R11(TANHD)
#undef TANHD
  }

  // ---------------- 3 GRU iterations ----------------
  for (int it = 0; it < 3; ++it) {
    // n-messages from OLD h's (scalars; A entries are wave-uniform broadcasts)
    const float nR = DOT_O(1);
#define DECLNO(i) const float nO1_##i = sA[(1 + i) * 22] * hR; \
                  const float nO2_##i = DOT_D((1 + i) * 22 + 11);
    R10(DECLNO)
#undef DECLNO
#define DECLND(i) const float nD##i = DOT_O((11 + i) * 22 + 1);
    R11(DECLND)
#undef DECLND

    // ---- gate R (1 row, K=128) ----
    __syncthreads();
    smem[c] = hR;
    smem[64 + c] = nR;
    __syncthreads();
    {
      float az = 0.f, ar = 0.f;
      for (int k4 = 0; k4 < 128; k4 += 4) {
        const float wa0 = WzR[(k4 + 0) * 64 + c], wa1 = WzR[(k4 + 1) * 64 + c];
        const float wa2 = WzR[(k4 + 2) * 64 + c], wa3 = WzR[(k4 + 3) * 64 + c];
        const float wb0 = WrR[(k4 + 0) * 64 + c], wb1 = WrR[(k4 + 1) * 64 + c];
        const float wb2 = WrR[(k4 + 2) * 64 + c], wb3 = WrR[(k4 + 3) * 64 + c];
        const float4 v = *reinterpret_cast<const float4*>(&smem[k4]);
        az = fmaf(v.x, wa0, az); az = fmaf(v.y, wa1, az);
        az = fmaf(v.z, wa2, az); az = fmaf(v.w, wa3, az);
        ar = fmaf(v.x, wb0, ar); ar = fmaf(v.y, wb1, ar);
        ar = fmaf(v.z, wb2, ar); ar = fmaf(v.w, wb3, ar);
      }
      const float z = sigmoidf_(az);
      const float r = sigmoidf_(ar);
      __syncthreads();
      smem[c] = hR * r;
      __syncthreads();
      float am = bmR[c];
      for (int k4 = 0; k4 < 128; k4 += 4) {
        const float w0 = WmR[(k4 + 0) * 64 + c], w1 = WmR[(k4 + 1) * 64 + c];
        const float w2 = WmR[(k4 + 2) * 64 + c], w3 = WmR[(k4 + 3) * 64 + c];
        const float4 v = *reinterpret_cast<const float4*>(&smem[k4]);
        am = fmaf(v.x, w0, am); am = fmaf(v.y, w1, am);
        am = fmaf(v.z, w2, am); am = fmaf(v.w, w3, am);
      }
      hR = (1.f - z) * hR + z * tanhf(am);
    }

    // ---- gate O (10 rows, K=192) ----
    __syncthreads();
#define STAGEO(i) smem[i * 192 + c] = hO##i; \
                  smem[i * 192 + 64 + c] = nO1_##i; \
                  smem[i * 192 + 128 + c] = nO2_##i;
    R10(STAGEO)
#undef STAGEO
    __syncthreads();
    {
#define DECLZR(i) float az##i = 0.f, ar##i = 0.f;
      R10(DECLZR)
#undef DECLZR
      for (int k4 = 0; k4 < 192; k4 += 4) {
        const float wa0 = WzO[(k4 + 0) * 64 + c], wa1 = WzO[(k4 + 1) * 64 + c];
        const float wa2 = WzO[(k4 + 2) * 64 + c], wa3 = WzO[(k4 + 3) * 64 + c];
        const float wb0 = WrO[(k4 + 0) * 64 + c], wb1 = WrO[(k4 + 1) * 64 + c];
        const float wb2 = WrO[(k4 + 2) * 64 + c], wb3 = WrO[(k4 + 3) * 64 + c];
#define MSTEP(i) { const float4 v = *reinterpret_cast<const float4*>(&smem[i * 192 + k4]); \
        az##i = fmaf(v.x, wa0, az##i); az##i = fmaf(v.y, wa1, az##i); \
        az##i = fmaf(v.z, wa2, az##i); az##i = fmaf(v.w, wa3, az##i); \
        ar##i = fmaf(v.x, wb0, ar##i); ar##i = fmaf(v.y, wb1, ar##i); \
        ar##i = fmaf(v.z, wb2, ar##i); ar##i = fmaf(v.w, wb3, ar##i); }
        R10(MSTEP)
#undef MSTEP
      }
#define SIGZR(i) const float z##i = sigmoidf_(az##i); const float r##i = sigmoidf_(ar##i);
      R10(SIGZR)
#undef SIGZR
      __syncthreads();
#define STAGEHR(i) smem[i * 192 + c] = hO##i * r##i;
      R10(STAGEHR)
#undef STAGEHR
      __syncthreads();
#define DECLAM(i) float am##i = bmO[c];
      R10(DECLAM)
#undef DECLAM
      for (int k4 = 0; k4 < 192; k4 += 4) {
        const float w0 = WmO[(k4 + 0) * 64 + c], w1 = WmO[(k4 + 1) * 64 + c];
        const float w2 = WmO[(k4 + 2) * 64 + c], w3 = WmO[(k4 + 3) * 64 + c];
#define MSTEP(i) { const float4 v = *reinterpret_cast<const float4*>(&smem[i * 192 + k4]); \
        am##i = fmaf(v.x, w0, am##i); am##i = fmaf(v.y, w1, am##i); \
        am##i = fmaf(v.z, w2, am##i); am##i = fmaf(v.w, w3, am##i); }
        R10(MSTEP)
#undef MSTEP
      }
#define UPDO(i) hO##i = (1.f - z##i) * hO##i + z##i * tanhf(am##i);
      R10(UPDO)
#undef UPDO
    }

    // ---- gate D (11 rows, K=128) ----
    __syncthreads();
#define STAGED(i) smem[i * 128 + c] = hD##i; \
                  smem[i * 128 + 64 + c] = nD##i;
    R11(STAGED)
#undef STAGED
    __syncthreads();
    {
#define DECLZR(i) float az##i = 0.f, ar##i = 0.f;
      R11(DECLZR)
#undef DECLZR
      for (int k4 = 0; k4 < 128; k4 += 4) {
        const float wa0 = WzD[(k4 + 0) * 64 + c], wa1 = WzD[(k4 + 1) * 64 + c];
        const float wa2 = WzD[(k4 + 2) * 64 + c], wa3 = WzD[(k4 + 3) * 64 + c];
        const float wb0 = WrD[(k4 + 0) * 64 + c], wb1 = WrD[(k4 + 1) * 64 + c];
        const float wb2 = WrD[(k4 + 2) * 64 + c], wb3 = WrD[(k4 + 3) * 64 + c];
#define MSTEP(i) { const float4 v = *reinterpret_cast<const float4*>(&smem[i * 128 + k4]); \
        az##i = fmaf(v.x, wa0, az##i); az##i = fmaf(v.y, wa1, az##i); \
        az##i = fmaf(v.z, wa2, az##i); az##i = fmaf(v.w, wa3, az##i); \
        ar##i = fmaf(v.x, wb0, ar##i); ar##i = fmaf(v.y, wb1, ar##i); \
        ar##i = fmaf(v.z, wb2, ar##i); ar##i = fmaf(v.w, wb3, ar##i); }
        R11(MSTEP)
#undef MSTEP
      }
#define SIGZR(i) const float z##i = sigmoidf_(az##i); const float r##i = sigmoidf_(ar##i);
      R11(SIGZR)
#undef SIGZR
      __syncthreads();
#define STAGEHR(i) smem[i * 128 + c] = hD##i * r##i;
      R11(STAGEHR)
#undef STAGEHR
      __syncthreads();
#define DECLAM(i) float am##i = bmD[c];
      R11(DECLAM)
#undef DECLAM
      for (int k4 = 0; k4 < 128; k4 += 4) {
        const float w0 = WmD[(k4 + 0) * 64 + c], w1 = WmD[(k4 + 1) * 64 + c];
        const float w2 = WmD[(k4 + 2) * 64 + c], w3 = WmD[(k4 + 3) * 64 + c];
#define MSTEP(i) { const float4 v = *reinterpret_cast<const float4*>(&smem[i * 128 + k4]); \
        am##i = fmaf(v.x, w0, am##i); am##i = fmaf(v.y, w1, am##i); \
        am##i = fmaf(v.z, w2, am##i); am##i = fmaf(v.w, w3, am##i); }
        R11(MSTEP)
#undef MSTEP
      }
#define UPDD(i) hD##i = (1.f - z##i) * hD##i + z##i * tanhf(am##i);
      R11(UPDD)
#undef UPDD
    }
  }

  // ---------------- scores ----------------
  __syncthreads();
  smem[c] = hR;
#define STASH_O(i) smem[(1 + i) * 64 + c] = hO##i;
  R10(STASH_O)
#undef STASH_O
#define STASH_D(i) smem[(11 + i) * 64 + c] = hD##i;
  R11(STASH_D)
#undef STASH_D
  __syncthreads();

  const int g = c >> 4;    // row-group 0..3
  const int c1 = c & 15;   // hidden-1 column
  float pR = 0.f, pO = 0.f, pD = 0.f;
  for (int rr = g; rr < 22; rr += 4) {
    const float* W1; const float* b1; const float* W2;
    if (rr == 0)      { W1 = W1R; b1 = b1R; W2 = W2R; }
    else if (rr < 11) { W1 = W1O; b1 = b1O; W2 = W2O; }
    else              { W1 = W1D; b1 = b1D; W2 = W2D; }
    float a = b1[c1];
#pragma unroll
    for (int kk = 0; kk < 64; ++kk) {
      const int k = (kk + (g << 4)) & 63;  // stagger to dodge LDS bank aliasing
      a = fmaf(smem[rr * 64 + k], W1[k * 16 + c1], a);
    }
    const float t = tanhf(a) * W2[c1];
    if (rr == 0) pR += t;
    else if (rr < 11) pO += t;
    else pD += t;
  }
#pragma unroll
  for (int off = 32; off >= 1; off >>= 1) {
    pR += __shfl_xor(pR, off, 64);
    pO += __shfl_xor(pO, off, 64);
    pD += __shfl_xor(pD, off, 64);
  }
  if (c < 60) {
    out[(size_t)b * 60 + c] = pR * tp[c] + pO * tp[60 + c] + pD * tp[120 + c];
  }
}

extern "C" void kernel_launch(void* const* d_in, const int* in_sizes, int n_in,
                              void* d_out, int out_size, void* d_ws, size_t ws_size,
                              hipStream_t stream) {
  const float* X   = (const float*)d_in[0];
  const float* A   = (const float*)d_in[1];
  const float* WgR = (const float*)d_in[2];
  const float* bgR = (const float*)d_in[3];
  const float* WgO = (const float*)d_in[4];
  const float* bgO = (const float*)d_in[5];
  const float* WgD = (const float*)d_in[6];
  const float* bgD = (const float*)d_in[7];
  const float* WzR = (const float*)d_in[8];
  const float* WrR = (const float*)d_in[9];
  const float* WmR = (const float*)d_in[10];
  const float* bmR = (const float*)d_in[11];
  const float* WzO = (const float*)d_in[12];
  const float* WrO = (const float*)d_in[13];
  const float* WmO = (const float*)d_in[14];
  const float* bmO = (const float*)d_in[15];
  const float* WzD = (const float*)d_in[16];
  const float* WrD = (const float*)d_in[17];
  const float* WmD = (const float*)d_in[18];
  const float* bmD = (const float*)d_in[19];
  const float* W1R = (const float*)d_in[20];
  const float* b1R = (const float*)d_in[21];
  const float* W2R = (const float*)d_in[22];
  const float* W1O = (const float*)d_in[23];
  const float* b1O = (const float*)d_in[24];
  const float* W2O = (const float*)d_in[25];
  const float* W1D = (const float*)d_in[26];
  const float* b1D = (const float*)d_in[27];
  const float* W2D = (const float*)d_in[28];
  const float* Tmp = (const float*)d_in[29];
  const float* GK  = (const float*)d_in[30];
  const float* GRK = (const float*)d_in[31];
  const float* GB  = (const float*)d_in[32];
  const float* WO  = (const float*)d_in[33];
  const int*   IDX = (const int*)d_in[34];

  float* tp = (float*)d_ws;  // 3*60 floats
  const int B = in_sizes[0] / 880;

  hipLaunchKernelGGL(temporal_kernel, dim3(1), dim3(64), 0, stream, Tmp, GK, GRK, GB, WO, IDX, tp);
  hipLaunchKernelGGL(ggnn_main, dim3(B), dim3(64), 0, stream,
                     X, A, WgR, bgR, WgO, bgO, WgD, bgD,
                     WzR, WrR, WmR, bmR, WzO, WrO, WmO, bmO, WzD, WrD, WmD, bmD,
                     W1R, b1R, W2R, W1O, b1O, W2O, W1D, b1D, W2D,
                     tp, (float*)d_out);
}

// Round 4
// 1075.834 us; speedup vs baseline: 1.6693x; 1.6693x over previous
//
#include <hip/hip_runtime.h>
#include <hip/hip_bf16.h>
#include <math.h>

#define DEV __device__ __forceinline__

DEV float sigmoidf_(float x) { return 1.0f / (1.0f + __expf(-x)); }

// Row-iteration macros: every per-row access is a literal constant index.
#define R10(OP) OP(0) OP(1) OP(2) OP(3) OP(4) OP(5) OP(6) OP(7) OP(8) OP(9)
#define R11(OP) R10(OP) OP(10)

// dot of sA[base..base+9] with hO scalars (sA entries are wave-uniform)
#define DOT_O(base) (sA[(base)+0]*hO0 + sA[(base)+1]*hO1 + sA[(base)+2]*hO2 + sA[(base)+3]*hO3 \
                   + sA[(base)+4]*hO4 + sA[(base)+5]*hO5 + sA[(base)+6]*hO6 + sA[(base)+7]*hO7 \
                   + sA[(base)+8]*hO8 + sA[(base)+9]*hO9)
// dot of sA[base..base+10] with hD scalars
#define DOT_D(base) (sA[(base)+0]*hD0 + sA[(base)+1]*hD1 + sA[(base)+2]*hD2 + sA[(base)+3]*hD3 \
                   + sA[(base)+4]*hD4 + sA[(base)+5]*hD5 + sA[(base)+6]*hD6 + sA[(base)+7]*hD7 \
                   + sA[(base)+8]*hD8 + sA[(base)+9]*hD9 + sA[(base)+10]*hD10)

DEV float gstep(float x, float h, const float* k, const float* rk, const float* bb) {
  const float z  = sigmoidf_(fmaf(x, k[0], bb[0]) + fmaf(h, rk[0], bb[3]));
  const float r  = sigmoidf_(fmaf(x, k[1], bb[1]) + fmaf(h, rk[1], bb[4]));
  const float hh = tanhf(fmaf(x, k[2], bb[2]) + r * fmaf(h, rk[2], bb[5]));
  return z * h + (1.f - z) * hh;
}

// 3 tiny sequential bidirectional GRU chains + softmax + gather -> tp[3][60]
__global__ void __launch_bounds__(64, 1)
temporal_kernel(const float* __restrict__ T, const float* __restrict__ GK,
                const float* __restrict__ GRK, const float* __restrict__ GB,
                const float* __restrict__ WO, const int* __restrict__ IDX,
                float* __restrict__ tp) {
  const int i = threadIdx.x;
  __shared__ float fb[3][75];
  __shared__ float gg[3][75];
  if (i < 3) {
    float k0[3], k1[3], rk0[3], rk1[3];
#pragma unroll
    for (int q = 0; q < 3; ++q) {
      k0[q]  = GK[i * 6 + q];      k1[q]  = GK[i * 6 + 3 + q];
      rk0[q] = GRK[i * 6 + q];     rk1[q] = GRK[i * 6 + 3 + q];
    }
    const float* B0 = GB + i * 12;
    const float* B1 = GB + i * 12 + 6;
    float h = 0.f;
    for (int s = 0; s < 75; ++s) { h = gstep(T[i * 75 + s], h, k0, rk0, B0); fb[i][s] = h; }
    h = 0.f;
    for (int s = 0; s < 75; ++s) { h = gstep(fb[i][74 - s], h, k1, rk1, B1); gg[i][s] = h; }
    const float wo = WO[i];
    float mx = -1e30f;
    for (int s = 0; s < 75; ++s) mx = fmaxf(mx, gg[i][s] * wo);
    float sum = 0.f;
    for (int s = 0; s < 75; ++s) { const float e = __expf(gg[i][s] * wo - mx); fb[i][s] = e; sum += e; }
    const float inv = 1.f / sum;
    for (int j = 0; j < 60; ++j) tp[i * 60 + j] = fb[i][IDX[j]] * inv;
  }
}

// LDS layout for gate staging (floats):
//   RSLOT:  [0..127]              gate-R operand [hR | nR]
//   OSLOT:  [128 + i*192], i<10   gate-O operand [hO_i | nO1_i | nO2_i]
//   DSLOT:  [2048 + i*128], i<11  gate-D operand [hD_i | nD_i]
// Phase0 X stage reuses [0..879] (dead before first GRU iteration staging).
#define RSLOT 0
#define OSLOT 128
#define DSLOT 2048
#define SMEMN 3456

// One wave (64 threads) per batch element. lane = feature column c.
// Only the 22 h scalars persist in registers across gate phases; all gate
// operands are parked in LDS at the top of each iteration (spill killer).
__global__ void __launch_bounds__(64, 2) ggnn_main(
    const float* __restrict__ X, const float* __restrict__ A,
    const float* __restrict__ WgR, const float* __restrict__ bgR,
    const float* __restrict__ WgO, const float* __restrict__ bgO,
    const float* __restrict__ WgD, const float* __restrict__ bgD,
    const float* __restrict__ WzR, const float* __restrict__ WrR,
    const float* __restrict__ WmR, const float* __restrict__ bmR,
    const float* __restrict__ WzO, const float* __restrict__ WrO,
    const float* __restrict__ WmO, const float* __restrict__ bmO,
    const float* __restrict__ WzD, const float* __restrict__ WrD,
    const float* __restrict__ WmD, const float* __restrict__ bmD,
    const float* __restrict__ W1R, const float* __restrict__ b1R, const float* __restrict__ W2R,
    const float* __restrict__ W1O, const float* __restrict__ b1O, const float* __restrict__ W2O,
    const float* __restrict__ W1D, const float* __restrict__ b1D, const float* __restrict__ W2D,
    const float* __restrict__ tp, float* __restrict__ out) {
  const int b = blockIdx.x;
  const int c = threadIdx.x;  // 0..63

  __shared__ __align__(16) float smem[SMEMN];
  __shared__ float sA[484];  // A[b] 22x22

  const float* Xb = X + (size_t)b * 880;
  const float* Ab = A + (size_t)b * 484;
  for (int t = c; t < 880; t += 64) smem[t] = Xb[t];
  for (int t = c; t < 484; t += 64) sA[t] = Ab[t];
  __syncthreads();

  // ---------------- phase 0: h = tanh(Xg @ Wg + bg) ----------------
  float hR;
#define DECLHO(i) float hO##i;
  R10(DECLHO)
#undef DECLHO
#define DECLHD(i) float hD##i;
  R11(DECLHD)
#undef DECLHD
  {
    float aR = bgR[c], cO = bgO[c], cD = bgD[c];
#pragma unroll 4
    for (int k = 0; k < 40; ++k) {
      const float x = smem[k];  // X[b,0,k] broadcast
      aR = fmaf(x, WgR[k * 64 + c], aR);
      cO = fmaf(x, WgO[k * 64 + c], cO);
      cD = fmaf(x, WgD[k * 64 + c], cD);
    }
    hR = tanhf(aR);
#define DECLAO(i) float aO##i = cO;
    R10(DECLAO)
#undef DECLAO
#define DECLAD(i) float aD##i = cD;
    R11(DECLAD)
#undef DECLAD
#pragma unroll 2
    for (int k = 0; k < 30; ++k) {
      const float wo_ = WgO[(40 + k) * 64 + c];
      const float wd_ = WgD[(40 + k) * 64 + c];
#define AOSTEP(i) aO##i = fmaf(smem[(1 + i) * 40 + 10 + k], wo_, aO##i);
      R10(AOSTEP)
#undef AOSTEP
#define ADSTEP(i) aD##i = fmaf(smem[(11 + i) * 40 + 10 + k], wd_, aD##i);
      R11(ADSTEP)
#undef ADSTEP
    }
#define TANHO(i) hO##i = tanhf(aO##i);
    R10(TANHO)
#undef TANHO
#define TANHD(i) hD##i = tanhf(aD##i);
    R11(TANHD)
#undef TANHD
  }

  // ---------------- 3 GRU iterations ----------------
  for (int it = 0; it < 3; ++it) {
    // ---- stage ALL gate operands from OLD h (n never lives in regs across phases)
    __syncthreads();  // prior-iteration LDS reads done
    smem[RSLOT + c] = hR;
    smem[RSLOT + 64 + c] = DOT_O(1);
#define STAGEO(i) smem[OSLOT + i * 192 + c] = hO##i; \
                  smem[OSLOT + i * 192 + 64 + c] = sA[(1 + i) * 22] * hR; \
                  smem[OSLOT + i * 192 + 128 + c] = DOT_D((1 + i) * 22 + 11);
    R10(STAGEO)
#undef STAGEO
#define STAGEDD(i) smem[DSLOT + i * 128 + c] = hD##i; \
                   smem[DSLOT + i * 128 + 64 + c] = DOT_O((11 + i) * 22 + 1);
    R11(STAGEDD)
#undef STAGEDD
    __syncthreads();

    // ---- gate R (1 row, K=128) ----
    {
      float az = 0.f, ar = 0.f;
#pragma unroll 2
      for (int k4 = 0; k4 < 128; k4 += 4) {
        const float wa0 = WzR[(k4 + 0) * 64 + c], wa1 = WzR[(k4 + 1) * 64 + c];
        const float wa2 = WzR[(k4 + 2) * 64 + c], wa3 = WzR[(k4 + 3) * 64 + c];
        const float wb0 = WrR[(k4 + 0) * 64 + c], wb1 = WrR[(k4 + 1) * 64 + c];
        const float wb2 = WrR[(k4 + 2) * 64 + c], wb3 = WrR[(k4 + 3) * 64 + c];
        const float4 v = *reinterpret_cast<const float4*>(&smem[RSLOT + k4]);
        az = fmaf(v.x, wa0, az); az = fmaf(v.y, wa1, az);
        az = fmaf(v.z, wa2, az); az = fmaf(v.w, wa3, az);
        ar = fmaf(v.x, wb0, ar); ar = fmaf(v.y, wb1, ar);
        ar = fmaf(v.z, wb2, ar); ar = fmaf(v.w, wb3, ar);
      }
      const float z = sigmoidf_(az);
      const float r = sigmoidf_(ar);
      __syncthreads();
      smem[RSLOT + c] = hR * r;
      __syncthreads();
      float am = bmR[c];
#pragma unroll 2
      for (int k4 = 0; k4 < 128; k4 += 4) {
        const float w0 = WmR[(k4 + 0) * 64 + c], w1 = WmR[(k4 + 1) * 64 + c];
        const float w2 = WmR[(k4 + 2) * 64 + c], w3 = WmR[(k4 + 3) * 64 + c];
        const float4 v = *reinterpret_cast<const float4*>(&smem[RSLOT + k4]);
        am = fmaf(v.x, w0, am); am = fmaf(v.y, w1, am);
        am = fmaf(v.z, w2, am); am = fmaf(v.w, w3, am);
      }
      hR = (1.f - z) * hR + z * tanhf(am);
    }

    // ---- gate O (10 rows, K=192) ----
    {
#define DECLZR(i) float az##i = 0.f, ar##i = 0.f;
      R10(DECLZR)
#undef DECLZR
#pragma unroll 2
      for (int k4 = 0; k4 < 192; k4 += 4) {
        const float wa0 = WzO[(k4 + 0) * 64 + c], wa1 = WzO[(k4 + 1) * 64 + c];
        const float wa2 = WzO[(k4 + 2) * 64 + c], wa3 = WzO[(k4 + 3) * 64 + c];
        const float wb0 = WrO[(k4 + 0) * 64 + c], wb1 = WrO[(k4 + 1) * 64 + c];
        const float wb2 = WrO[(k4 + 2) * 64 + c], wb3 = WrO[(k4 + 3) * 64 + c];
#define MSTEP(i) { const float4 v = *reinterpret_cast<const float4*>(&smem[OSLOT + i * 192 + k4]); \
        az##i = fmaf(v.x, wa0, az##i); az##i = fmaf(v.y, wa1, az##i); \
        az##i = fmaf(v.z, wa2, az##i); az##i = fmaf(v.w, wa3, az##i); \
        ar##i = fmaf(v.x, wb0, ar##i); ar##i = fmaf(v.y, wb1, ar##i); \
        ar##i = fmaf(v.z, wb2, ar##i); ar##i = fmaf(v.w, wb3, ar##i); }
        R10(MSTEP)
#undef MSTEP
      }
#define SIGZR(i) const float z##i = sigmoidf_(az##i); const float r##i = sigmoidf_(ar##i);
      R10(SIGZR)
#undef SIGZR
      __syncthreads();
#define STAGEHR(i) smem[OSLOT + i * 192 + c] = hO##i * r##i;
      R10(STAGEHR)
#undef STAGEHR
      __syncthreads();
#define DECLAM(i) float am##i = bmO[c];
      R10(DECLAM)
#undef DECLAM
#pragma unroll 2
      for (int k4 = 0; k4 < 192; k4 += 4) {
        const float w0 = WmO[(k4 + 0) * 64 + c], w1 = WmO[(k4 + 1) * 64 + c];
        const float w2 = WmO[(k4 + 2) * 64 + c], w3 = WmO[(k4 + 3) * 64 + c];
#define MSTEP(i) { const float4 v = *reinterpret_cast<const float4*>(&smem[OSLOT + i * 192 + k4]); \
        am##i = fmaf(v.x, w0, am##i); am##i = fmaf(v.y, w1, am##i); \
        am##i = fmaf(v.z, w2, am##i); am##i = fmaf(v.w, w3, am##i); }
        R10(MSTEP)
#undef MSTEP
      }
#define UPDO(i) hO##i = (1.f - z##i) * hO##i + z##i * tanhf(am##i);
      R10(UPDO)
#undef UPDO
    }

    // ---- gate D (11 rows, K=128) ----
    {
#define DECLZR(i) float az##i = 0.f, ar##i = 0.f;
      R11(DECLZR)
#undef DECLZR
#pragma unroll 2
      for (int k4 = 0; k4 < 128; k4 += 4) {
        const float wa0 = WzD[(k4 + 0) * 64 + c], wa1 = WzD[(k4 + 1) * 64 + c];
        const float wa2 = WzD[(k4 + 2) * 64 + c], wa3 = WzD[(k4 + 3) * 64 + c];
        const float wb0 = WrD[(k4 + 0) * 64 + c], wb1 = WrD[(k4 + 1) * 64 + c];
        const float wb2 = WrD[(k4 + 2) * 64 + c], wb3 = WrD[(k4 + 3) * 64 + c];
#define MSTEP(i) { const float4 v = *reinterpret_cast<const float4*>(&smem[DSLOT + i * 128 + k4]); \
        az##i = fmaf(v.x, wa0, az##i); az##i = fmaf(v.y, wa1, az##i); \
        az##i = fmaf(v.z, wa2, az##i); az##i = fmaf(v.w, wa3, az##i); \
        ar##i = fmaf(v.x, wb0, ar##i); ar##i = fmaf(v.y, wb1, ar##i); \
        ar##i = fmaf(v.z, wb2, ar##i); ar##i = fmaf(v.w, wb3, ar##i); }
        R11(MSTEP)
#undef MSTEP
      }
#define SIGZR(i) const float z##i = sigmoidf_(az##i); const float r##i = sigmoidf_(ar##i);
      R11(SIGZR)
#undef SIGZR
      __syncthreads();
#define STAGEHR(i) smem[DSLOT + i * 128 + c] = hD##i * r##i;
      R11(STAGEHR)
#undef STAGEHR
      __syncthreads();
#define DECLAM(i) float am##i = bmD[c];
      R11(DECLAM)
#undef DECLAM
#pragma unroll 2
      for (int k4 = 0; k4 < 128; k4 += 4) {
        const float w0 = WmD[(k4 + 0) * 64 + c], w1 = WmD[(k4 + 1) * 64 + c];
        const float w2 = WmD[(k4 + 2) * 64 + c], w3 = WmD[(k4 + 3) * 64 + c];
#define MSTEP(i) { const float4 v = *reinterpret_cast<const float4*>(&smem[DSLOT + i * 128 + k4]); \
        am##i = fmaf(v.x, w0, am##i); am##i = fmaf(v.y, w1, am##i); \
        am##i = fmaf(v.z, w2, am##i); am##i = fmaf(v.w, w3, am##i); }
        R11(MSTEP)
#undef MSTEP
      }
#define UPDD(i) hD##i = (1.f - z##i) * hD##i + z##i * tanhf(am##i);
      R11(UPDD)
#undef UPDD
    }
  }

  // ---------------- scores ----------------
  __syncthreads();
  smem[c] = hR;
#define STASH_O(i) smem[(1 + i) * 64 + c] = hO##i;
  R10(STASH_O)
#undef STASH_O
#define STASH_D(i) smem[(11 + i) * 64 + c] = hD##i;
  R11(STASH_D)
#undef STASH_D
  __syncthreads();

  const int g = c >> 4;    // row-group 0..3
  const int c1 = c & 15;   // hidden-1 column
  float pR = 0.f, pO = 0.f, pD = 0.f;
  for (int rr = g; rr < 22; rr += 4) {
    const float* W1; const float* b1; const float* W2;
    if (rr == 0)      { W1 = W1R; b1 = b1R; W2 = W2R; }
    else if (rr < 11) { W1 = W1O; b1 = b1O; W2 = W2O; }
    else              { W1 = W1D; b1 = b1D; W2 = W2D; }
    float a = b1[c1];
#pragma unroll 8
    for (int kk = 0; kk < 64; ++kk) {
      const int k = (kk + (g << 4)) & 63;  // stagger to dodge LDS bank aliasing
      a = fmaf(smem[rr * 64 + k], W1[k * 16 + c1], a);
    }
    const float t = tanhf(a) * W2[c1];
    if (rr == 0) pR += t;
    else if (rr < 11) pO += t;
    else pD += t;
  }
#pragma unroll
  for (int off = 32; off >= 1; off >>= 1) {
    pR += __shfl_xor(pR, off, 64);
    pO += __shfl_xor(pO, off, 64);
    pD += __shfl_xor(pD, off, 64);
  }
  if (c < 60) {
    out[(size_t)b * 60 + c] = pR * tp[c] + pO * tp[60 + c] + pD * tp[120 + c];
  }
}

extern "C" void kernel_launch(void* const* d_in, const int* in_sizes, int n_in,
                              void* d_out, int out_size, void* d_ws, size_t ws_size,
                              hipStream_t stream) {
  const float* X   = (const float*)d_in[0];
  const float* A   = (const float*)d_in[1];
  const float* WgR = (const float*)d_in[2];
  const float* bgR = (const float*)d_in[3];
  const float* WgO = (const float*)d_in[4];
  const float* bgO = (const float*)d_in[5];
  const float* WgD = (const float*)d_in[6];
  const float* bgD = (const float*)d_in[7];
  const float* WzR = (const float*)d_in[8];
  const float* WrR = (const float*)d_in[9];
  const float* WmR = (const float*)d_in[10];
  const float* bmR = (const float*)d_in[11];
  const float* WzO = (const float*)d_in[12];
  const float* WrO = (const float*)d_in[13];
  const float* WmO = (const float*)d_in[14];
  const float* bmO = (const float*)d_in[15];
  const float* WzD = (const float*)d_in[16];
  const float* WrD = (const float*)d_in[17];
  const float* WmD = (const float*)d_in[18];
  const float* bmD = (const float*)d_in[19];
  const float* W1R = (const float*)d_in[20];
  const float* b1R = (const float*)d_in[21];
  const float* W2R = (const float*)d_in[22];
  const float* W1O = (const float*)d_in[23];
  const float* b1O = (const float*)d_in[24];
  const float* W2O = (const float*)d_in[25];
  const float* W1D = (const float*)d_in[26];
  const float* b1D = (const float*)d_in[27];
  const float* W2D = (const float*)d_in[28];
  const float* Tmp = (const float*)d_in[29];
  const float* GK  = (const float*)d_in[30];
  const float* GRK = (const float*)d_in[31];
  const float* GB  = (const float*)d_in[32];
  const float* WO  = (const float*)d_in[33];
  const int*   IDX = (const int*)d_in[34];

  float* tp = (float*)d_ws;  // 3*60 floats
  const int B = in_sizes[0] / 880;

  hipLaunchKernelGGL(temporal_kernel, dim3(1), dim3(64), 0, stream, Tmp, GK, GRK, GB, WO, IDX, tp);
  hipLaunchKernelGGL(ggnn_main, dim3(B), dim3(64), 0, stream,
                     X, A, WgR, bgR, WgO, bgO, WgD, bgD,
                     WzR, WrR, WmR, bmR, WzO, WrO, WmO, bmO, WzD, WrD, WmD, bmD,
                     W1R, b1R, W2R, W1O, b1O, W2O, W1D, b1D, W2D,
                     tp, (float*)d_out);
}